// Round 18
// baseline (1040.283 us; speedup 1.0000x reference)
//
// Round 18: BK=64 (two kt per barrier phase) — halves barrier count. Enabled
// by r17's B-in-registers: A-only LDS staging keeps LDS at 32KB (4 blocks/CU),
// avoiding the m132/r13 occupancy collapse. B register dbuf bA[8]/bB[8],
// statically named (rule #20). Filter+refine machinery unchanged.
#include <hip/hip_runtime.h>
#include <cstdint>
#include <cstddef>

#define K_DIM 512
#define BM 128
#define BN 128
#define JCHUNKS 8
#define LIST_MAX 4096
#define WINDOW 4.0f
#define NSLICE 32
#define REF_GRID 1024

typedef __attribute__((ext_vector_type(8))) _Float16 f16x8;
typedef __attribute__((ext_vector_type(8))) __bf16 bf16x8;
typedef __attribute__((ext_vector_type(8))) short short8;
typedef __attribute__((ext_vector_type(4))) float f32x4;

// ---------------------------------------------------------------------------
// Kernel 0: row norms + init vmin/vminx/counter/maxout.
// ---------------------------------------------------------------------------
__global__ __launch_bounds__(256) void norms_init_kernel(
    const float* __restrict__ A, const float* __restrict__ B,
    float* __restrict__ na, float* __restrict__ nb,
    unsigned* __restrict__ vmin, unsigned* __restrict__ vminx,
    int* __restrict__ counter, unsigned* __restrict__ maxout,
    int N, int M, int Npad, int Mpad)
{
    if (blockIdx.x == 0) {                       // one-time small-state init
        for (int c = threadIdx.x; c < LIST_MAX; c += 256)
            vminx[c] = 0x7f800000u;
        if (threadIdx.x == 0) { *counter = 0; *maxout = 0u; }
    }
    int w = (int)((blockIdx.x * blockDim.x + threadIdx.x) >> 6);
    int lane = threadIdx.x & 63;
    if (w >= Npad + Mpad) return;
    if (w < Npad) {
        float s = 0.f;
        if (w < N) {
            const float* src = A + (size_t)w * K_DIM + lane * 8;
            float4 v0 = *(const float4*)src;
            float4 v1 = *(const float4*)(src + 4);
            s = v0.x*v0.x + v0.y*v0.y + v0.z*v0.z + v0.w*v0.w
              + v1.x*v1.x + v1.y*v1.y + v1.z*v1.z + v1.w*v1.w;
            #pragma unroll
            for (int m = 1; m < 64; m <<= 1) s += __shfl_xor(s, m, 64);
        }
        if (lane == 0) { na[w] = s; vmin[w] = 0x7f800000u; }
    } else {
        int j = w - Npad;
        float s = __builtin_inff();   // padded centers never win the min
        if (j < M) {
            const float* src = B + (size_t)j * K_DIM + lane * 8;
            float4 v0 = *(const float4*)src;
            float4 v1 = *(const float4*)(src + 4);
            s = v0.x*v0.x + v0.y*v0.y + v0.z*v0.z + v0.w*v0.w
              + v1.x*v1.x + v1.y*v1.y + v1.z*v1.z + v1.w*v1.w;
            #pragma unroll
            for (int m = 1; m < 64; m <<= 1) s += __shfl_xor(s, m, 64);
        }
        if (lane == 0) nb[j] = s;
    }
}

// ---------------------------------------------------------------------------
// Kernel 1: preconvert fp32 -> fp16 in the per-(tile,kt) image layout
// [tile][kt(32-wide)][g][m][8], 128-row tiles.
// ---------------------------------------------------------------------------
__global__ __launch_bounds__(256) void preconvert_f16_kernel(
    const float* __restrict__ src, ushort* __restrict__ outW,
    int realRows, int padRows)
{
    int c = blockIdx.x * 256 + threadIdx.x;            // chunk id
    int total = padRows * (K_DIM / 8);
    if (c >= total) return;
    int m    = c & (BM - 1);
    int g    = (c >> 7) & 3;
    int kt   = (c >> 9) & 15;
    int tile = c >> 13;
    int row  = tile * BM + m;
    int k    = kt * 32 + g * 8;
    float f[8];
    if (row < realRows) {
        float4 x0 = *(const float4*)(src + (size_t)row * K_DIM + k);
        float4 x1 = *(const float4*)(src + (size_t)row * K_DIM + k + 4);
        f[0]=x0.x; f[1]=x0.y; f[2]=x0.z; f[3]=x0.w;
        f[4]=x1.x; f[5]=x1.y; f[6]=x1.z; f[7]=x1.w;
    } else {
        #pragma unroll
        for (int q = 0; q < 8; ++q) f[q] = 0.f;
    }
    f16x8 h;
    #pragma unroll
    for (int q = 0; q < 8; ++q) h[q] = (_Float16)f[q];   // RTN
    *(f16x8*)(outW + (size_t)c * 8) = h;
}

// ---------------------------------------------------------------------------
// Kernel 2: 1-pass fp16 MFMA GEMM + fused row-min (approximate filter).
// BK=64 double-step: one barrier per TWO kt panels. A: LDS dbuf 2x16KB via
// global_load_lds (adjacent panels are contiguous). B: register dbuf
// bA[8]/bB[8] prefetched one double-step ahead (statically named).
// ---------------------------------------------------------------------------
__global__ __launch_bounds__(256, 4) void gemm_min_f16(
    const ushort* __restrict__ AhW, const ushort* __restrict__ BhW,
    const float* __restrict__ na, const float* __restrict__ nb,
    unsigned* __restrict__ vmin, int N, int njt)
{
    __shared__ ushort Ah[2][8192];   // 32 KB (two kt panels per buffer)

    const int tid  = threadIdx.x;
    const int lane = tid & 63;
    const int wave = tid >> 6;
    const int wr = (wave >> 1) * 64;
    const int wc = (wave & 1) * 64;
    const int tr = lane & 15;
    const int tg = lane >> 4;
    const int tile = blockIdx.y;          // A-tile (slow axis)

    const int per = (njt + JCHUNKS - 1) / JCHUNKS;
    const int jt_begin = min((int)blockIdx.x * per, njt);   // chunk = fast axis
    const int jt_end   = min(jt_begin + per, njt);

    float localmin[16];
    #pragma unroll
    for (int u = 0; u < 16; ++u) localmin[u] = __builtin_inff();

    auto STAGE_A = [&](int buf, int d) {          // stage kt pair (d&7)*2, +1
        const int kt0 = (d & 7) * 2;
        const ushort* sA = AhW + ((size_t)tile * 16 + kt0) * 4096;  // 8192 contig
        #pragma unroll
        for (int q = 0; q < 4; ++q) {
            int gi = (q * 256 + tid) * 8;          // per-lane global offset
            int li = (q * 256 + wave * 64) * 8;    // wave-uniform LDS base
            __builtin_amdgcn_global_load_lds(
                (const __attribute__((address_space(1))) void*)(sA + gi),
                (__attribute__((address_space(3))) void*)(&Ah[buf][li]), 16, 0, 0);
        }
    };

    // per-lane B fragment base offset within a (jt,kt) panel (in ushorts)
    const size_t boff = ((size_t)tg * 128 + wc + tr) * 8;

    auto LOAD_B8 = [&](f16x8* dst, int d) {       // dst is a NAMED array
        const int jt  = jt_begin + (d >> 3);
        const int kt0 = (d & 7) * 2;
        const ushort* sB = BhW + ((size_t)jt * 16 + kt0) * 4096 + boff;
        #pragma unroll
        for (int h = 0; h < 2; ++h)
            #pragma unroll
            for (int fj = 0; fj < 4; ++fj)
                dst[h * 4 + fj] =
                    *(const f16x8*)(sB + (size_t)h * 4096 + (size_t)fj * 128);
    };

    if (jt_begin < jt_end) {
        const int T2 = (jt_end - jt_begin) * 8;   // double-steps (even count)

        STAGE_A(0, 0);
        f16x8 bA[8], bB[8];                       // register double buffer
        LOAD_B8(bA, 0);
        __syncthreads();                          // drain prologue A
        int cur = 0;

        f32x4 acc[4][4];
        #pragma unroll
        for (int fi = 0; fi < 4; ++fi)
            #pragma unroll
            for (int fj = 0; fj < 4; ++fj) acc[fi][fj] = (f32x4)0.f;

        for (int d = 0; d < T2; d += 2) {
            // -------- even phase d: consume bA, prefetch (d+1) --------
            {
                STAGE_A(cur ^ 1, d + 1);          // d+1 < T2 (T2 even)
                LOAD_B8(bB, d + 1);

                #pragma unroll
                for (int h = 0; h < 2; ++h) {
                    f16x8 a_[4];
                    #pragma unroll
                    for (int fi = 0; fi < 4; ++fi) {
                        int ra = h * 4096 + (tg * 128 + wr + fi * 16 + tr) * 8;
                        a_[fi] = *(const f16x8*)(&Ah[cur][ra]);
                    }
                    #pragma unroll
                    for (int fi = 0; fi < 4; ++fi)
                        #pragma unroll
                        for (int fj = 0; fj < 4; ++fj)
                            acc[fi][fj] = __builtin_amdgcn_mfma_f32_16x16x32_f16(
                                a_[fi], bA[h * 4 + fj], acc[fi][fj], 0, 0, 0);
                }
                // (d&7)==7 impossible for even d: no fold here
                __syncthreads();
                cur ^= 1;
            }
            // -------- odd phase d+1: consume bB, prefetch (d+2) --------
            {
                if (d + 2 < T2) {
                    STAGE_A(cur ^ 1, d + 2);
                    LOAD_B8(bA, d + 2);
                }

                #pragma unroll
                for (int h = 0; h < 2; ++h) {
                    f16x8 a_[4];
                    #pragma unroll
                    for (int fi = 0; fi < 4; ++fi) {
                        int ra = h * 4096 + (tg * 128 + wr + fi * 16 + tr) * 8;
                        a_[fi] = *(const f16x8*)(&Ah[cur][ra]);
                    }
                    #pragma unroll
                    for (int fi = 0; fi < 4; ++fi)
                        #pragma unroll
                        for (int fj = 0; fj < 4; ++fj)
                            acc[fi][fj] = __builtin_amdgcn_mfma_f32_16x16x32_f16(
                                a_[fi], bB[h * 4 + fj], acc[fi][fj], 0, 0, 0);
                }

                if (((d + 1) & 7) == 7) {         // end of a jt: fold row-min
                    const int jt = jt_begin + ((d + 1) >> 3);
                    #pragma unroll
                    for (int fj = 0; fj < 4; ++fj) {
                        int j = jt * BN + wc + fj * 16 + tr;
                        float nbv = nb[j];        // padded with +inf
                        #pragma unroll
                        for (int fi = 0; fi < 4; ++fi)
                            #pragma unroll
                            for (int r = 0; r < 4; ++r) {
                                float s = fmaf(-2.f, acc[fi][fj][r], nbv);
                                localmin[fi * 4 + r] = fminf(localmin[fi * 4 + r], s);
                            }
                    }
                    #pragma unroll
                    for (int fi = 0; fi < 4; ++fi)
                        #pragma unroll
                        for (int fj = 0; fj < 4; ++fj) acc[fi][fj] = (f32x4)0.f;
                }

                __syncthreads();
                cur ^= 1;
            }
        }
    }

    #pragma unroll
    for (int u = 0; u < 16; ++u) {
        float v = localmin[u];
        #pragma unroll
        for (int m = 1; m < 16; m <<= 1) v = fminf(v, __shfl_xor(v, m, 64));
        localmin[u] = v;
    }
    if (tr == 0) {
        #pragma unroll
        for (int fi = 0; fi < 4; ++fi)
            #pragma unroll
            for (int r = 0; r < 4; ++r) {
                int i = tile * BM + wr + fi * 16 + tg * 4 + r;
                if (i < N) {
                    float v = fmaxf(na[i] + localmin[fi * 4 + r], 0.f);
                    atomicMin(&vmin[i], __float_as_uint(v));
                }
            }
    }
}

// ---------------------------------------------------------------------------
// Kernel 2b: fallback (ws too small) — bf16 3-pass, 128x128, in-staging conv.
// ---------------------------------------------------------------------------
__global__ __launch_bounds__(256, 2) void gemm_min_fused(
    const float* __restrict__ A, const float* __restrict__ B,
    const float* __restrict__ na, const float* __restrict__ nb,
    unsigned* __restrict__ vmin, int N, int M, int njt)
{
    __shared__ ushort Ah[4096], Al[4096], Bh[4096], Bl[4096];

    const int tid  = threadIdx.x;
    const int lane = tid & 63;
    const int wave = tid >> 6;
    const int wr = (wave >> 1) * 64;
    const int wc = (wave & 1) * 64;
    const int tr = lane & 15;
    const int tg = lane >> 4;
    const int i0 = blockIdx.y * BM;

    const int sm = tid & 127;
    const int sh = tid >> 7;

    const int per = (njt + JCHUNKS - 1) / JCHUNKS;
    const int jt_begin = min((int)blockIdx.x * per, njt);
    const int jt_end   = min(jt_begin + per, njt);

    float localmin[16];
    #pragma unroll
    for (int u = 0; u < 16; ++u) localmin[u] = __builtin_inff();

    for (int jt = jt_begin; jt < jt_end; ++jt) {
        const int j0 = jt * BN;
        f32x4 acc[4][4];
        #pragma unroll
        for (int fi = 0; fi < 4; ++fi)
            #pragma unroll
            for (int fj = 0; fj < 4; ++fj) acc[fi][fj] = (f32x4)0.f;

        for (int kt = 0; kt < K_DIM / 32; ++kt) {
            const int k0 = kt * 32 + sh * 16;
            {
                float f[16];
                int gi = i0 + sm;
                if (gi < N) {
                    const float* p = A + (size_t)gi * K_DIM + k0;
                    #pragma unroll
                    for (int q = 0; q < 4; ++q) {
                        float4 x = *(const float4*)(p + q * 4);
                        f[q*4+0]=x.x; f[q*4+1]=x.y; f[q*4+2]=x.z; f[q*4+3]=x.w;
                    }
                } else {
                    #pragma unroll
                    for (int q = 0; q < 16; ++q) f[q] = 0.f;
                }
                short8 h0, h1, l0, l1;
                #pragma unroll
                for (int q = 0; q < 8; ++q) {
                    uint u = __float_as_uint(f[q]);
                    h0[q] = (short)(u >> 16);
                    float lo = f[q] - __uint_as_float(u & 0xffff0000u);
                    l0[q] = (short)(__float_as_uint(lo) >> 16);
                }
                #pragma unroll
                for (int q = 0; q < 8; ++q) {
                    uint u = __float_as_uint(f[8+q]);
                    h1[q] = (short)(u >> 16);
                    float lo = f[8+q] - __uint_as_float(u & 0xffff0000u);
                    l1[q] = (short)(__float_as_uint(lo) >> 16);
                }
                int g0 = sh * 2;
                *(short8*)(Ah + (g0 * 128 + sm) * 8)       = h0;
                *(short8*)(Ah + ((g0 + 1) * 128 + sm) * 8) = h1;
                *(short8*)(Al + (g0 * 128 + sm) * 8)       = l0;
                *(short8*)(Al + ((g0 + 1) * 128 + sm) * 8) = l1;
            }
            {
                float f[16];
                int gj = j0 + sm;
                if (gj < M) {
                    const float* p = B + (size_t)gj * K_DIM + k0;
                    #pragma unroll
                    for (int q = 0; q < 4; ++q) {
                        float4 x = *(const float4*)(p + q * 4);
                        f[q*4+0]=x.x; f[q*4+1]=x.y; f[q*4+2]=x.z; f[q*4+3]=x.w;
                    }
                } else {
                    #pragma unroll
                    for (int q = 0; q < 16; ++q) f[q] = 0.f;
                }
                short8 h0, h1, l0, l1;
                #pragma unroll
                for (int q = 0; q < 8; ++q) {
                    uint u = __float_as_uint(f[q]);
                    h0[q] = (short)(u >> 16);
                    float lo = f[q] - __uint_as_float(u & 0xffff0000u);
                    l0[q] = (short)(__float_as_uint(lo) >> 16);
                }
                #pragma unroll
                for (int q = 0; q < 8; ++q) {
                    uint u = __float_as_uint(f[8+q]);
                    h1[q] = (short)(u >> 16);
                    float lo = f[8+q] - __uint_as_float(u & 0xffff0000u);
                    l1[q] = (short)(__float_as_uint(lo) >> 16);
                }
                int g0 = sh * 2;
                *(short8*)(Bh + (g0 * 128 + sm) * 8)       = h0;
                *(short8*)(Bh + ((g0 + 1) * 128 + sm) * 8) = h1;
                *(short8*)(Bl + (g0 * 128 + sm) * 8)       = l0;
                *(short8*)(Bl + ((g0 + 1) * 128 + sm) * 8) = l1;
            }
            __syncthreads();

            bf16x8 a_h[4], a_l[4], b_h[4], b_l[4];
            #pragma unroll
            for (int fi = 0; fi < 4; ++fi) {
                int ra = (tg * 128 + wr + fi * 16 + tr) * 8;
                a_h[fi] = *(const bf16x8*)(Ah + ra);
                a_l[fi] = *(const bf16x8*)(Al + ra);
            }
            #pragma unroll
            for (int fj = 0; fj < 4; ++fj) {
                int rb = (tg * 128 + wc + fj * 16 + tr) * 8;
                b_h[fj] = *(const bf16x8*)(Bh + rb);
                b_l[fj] = *(const bf16x8*)(Bl + rb);
            }
            #pragma unroll
            for (int fi = 0; fi < 4; ++fi)
                #pragma unroll
                for (int fj = 0; fj < 4; ++fj) {
                    acc[fi][fj] = __builtin_amdgcn_mfma_f32_16x16x32_bf16(a_h[fi], b_h[fj], acc[fi][fj], 0, 0, 0);
                    acc[fi][fj] = __builtin_amdgcn_mfma_f32_16x16x32_bf16(a_h[fi], b_l[fj], acc[fi][fj], 0, 0, 0);
                    acc[fi][fj] = __builtin_amdgcn_mfma_f32_16x16x32_bf16(a_l[fi], b_h[fj], acc[fi][fj], 0, 0, 0);
                }
            __syncthreads();
        }

        #pragma unroll
        for (int fj = 0; fj < 4; ++fj) {
            int j = j0 + wc + fj * 16 + tr;
            float nbv = nb[j];
            #pragma unroll
            for (int fi = 0; fi < 4; ++fi)
                #pragma unroll
                for (int r = 0; r < 4; ++r) {
                    float s = fmaf(-2.f, acc[fi][fj][r], nbv);
                    localmin[fi * 4 + r] = fminf(localmin[fi * 4 + r], s);
                }
        }
    }

    #pragma unroll
    for (int u = 0; u < 16; ++u) {
        float v = localmin[u];
        #pragma unroll
        for (int m = 1; m < 16; m <<= 1) v = fminf(v, __shfl_xor(v, m, 64));
        localmin[u] = v;
    }
    if (tr == 0) {
        #pragma unroll
        for (int fi = 0; fi < 4; ++fi)
            #pragma unroll
            for (int r = 0; r < 4; ++r) {
                int i = i0 + wr + fi * 16 + tg * 4 + r;
                if (i < N) {
                    float v = fmaxf(na[i] + localmin[fi * 4 + r], 0.f);
                    atomicMin(&vmin[i], __float_as_uint(v));
                }
            }
    }
}

// ---------------------------------------------------------------------------
// Kernel 3: parallel max of vmin (128 blocks, device atomicMax).
// ---------------------------------------------------------------------------
__global__ __launch_bounds__(256) void maxred_kernel(
    const unsigned* __restrict__ vmin, unsigned* __restrict__ maxout, int N)
{
    unsigned best = 0u;
    for (int i = blockIdx.x * 256 + threadIdx.x; i < N; i += gridDim.x * 256) {
        unsigned v = vmin[i];
        if (v > best) best = v;
    }
    #pragma unroll
    for (int m = 1; m < 64; m <<= 1) {
        unsigned o = __shfl_xor(best, m, 64);
        if (o > best) best = o;
    }
    __shared__ unsigned sb[4];
    int lane = threadIdx.x & 63, w = threadIdx.x >> 6;
    if (lane == 0) sb[w] = best;
    __syncthreads();
    if (threadIdx.x == 0) {
        unsigned b = sb[0];
        #pragma unroll
        for (int w2 = 1; w2 < 4; ++w2) if (sb[w2] > b) b = sb[w2];
        atomicMax(maxout, b);
    }
}

// ---------------------------------------------------------------------------
// Kernel 4: collect candidate rows within WINDOW of the approx max.
// ---------------------------------------------------------------------------
__global__ __launch_bounds__(256) void cand_kernel(
    const unsigned* __restrict__ vmin, const unsigned* __restrict__ maxout,
    int* __restrict__ counter, int* __restrict__ list, int N)
{
    int i = blockIdx.x * 256 + threadIdx.x;
    if (i >= N) return;
    float thr = __uint_as_float(*maxout) - WINDOW;
    if (__uint_as_float(vmin[i]) >= thr) {
        int p = atomicAdd(counter, 1);
        if (p < LIST_MAX) list[p] = i;
    }
}

// ---------------------------------------------------------------------------
// Kernel 5: exact fp32 refinement, parallel over (candidate, j-slice).
// ---------------------------------------------------------------------------
__global__ __launch_bounds__(256) void refine_kernel(
    const float* __restrict__ A, const float* __restrict__ B,
    const float* __restrict__ na, const float* __restrict__ nb,
    const int* __restrict__ counter, const int* __restrict__ list,
    unsigned* __restrict__ vminx, int M)
{
    __shared__ float arow[K_DIM];
    __shared__ float sred[4];
    const int tid = threadIdx.x, lane = tid & 63, w = tid >> 6;
    int cnt = *counter;
    if (cnt > LIST_MAX) cnt = LIST_MAX;
    const int slice = (M + NSLICE - 1) / NSLICE;   // ~157

    for (int idx = blockIdx.x; idx < cnt * NSLICE; idx += gridDim.x) {
        const int c = idx / NSLICE;
        const int s = idx % NSLICE;
        const int i = list[c];
        const int j0 = s * slice;
        const int j1 = min(j0 + slice, M);

        __syncthreads();                           // protect arow/sred reuse
        for (int k = tid; k < K_DIM; k += 256)
            arow[k] = A[(size_t)i * K_DIM + k];
        __syncthreads();

        float4 a0 = *(const float4*)&arow[lane * 8];
        float4 a1 = *(const float4*)&arow[lane * 8 + 4];
        float lmin = __builtin_inff();
        for (int j = j0 + w; j < j1; j += 4) {     // wave w takes every 4th j
            const float* br = B + (size_t)j * K_DIM + lane * 8;
            float4 x0 = *(const float4*)br;
            float4 x1 = *(const float4*)(br + 4);
            float d = x0.x*a0.x + x0.y*a0.y + x0.z*a0.z + x0.w*a0.w
                    + x1.x*a1.x + x1.y*a1.y + x1.z*a1.z + x1.w*a1.w;
            #pragma unroll
            for (int m = 1; m < 64; m <<= 1) d += __shfl_xor(d, m, 64);
            float y = fmaf(-2.f, d, nb[j]);
            lmin = fminf(lmin, y);
        }
        if (lane == 0) sred[w] = lmin;
        __syncthreads();
        if (tid == 0) {
            float m2 = fminf(fminf(sred[0], sred[1]), fminf(sred[2], sred[3]));
            float v = fmaxf(na[i] + m2, 0.f);
            atomicMin(&vminx[c], __float_as_uint(v));
        }
    }
}

// ---------------------------------------------------------------------------
// Kernel 6: final — packed max over candidates' exact values, sqrt, write out.
// ---------------------------------------------------------------------------
__global__ __launch_bounds__(1024) void final_kernel(
    const int* __restrict__ counter, const int* __restrict__ list,
    const unsigned* __restrict__ vminx, float* __restrict__ out)
{
    int cnt = *counter;
    if (cnt > LIST_MAX) cnt = LIST_MAX;
    unsigned long long best = 0ull;
    for (int c = threadIdx.x; c < cnt; c += 1024) {
        unsigned long long p =
            ((unsigned long long)vminx[c] << 32) | (unsigned)(~list[c]);
        if (p > best) best = p;
    }
    #pragma unroll
    for (int m = 1; m < 64; m <<= 1) {
        unsigned hi = (unsigned)(best >> 32), lo = (unsigned)best;
        unsigned ohi = __shfl_xor(hi, m, 64);
        unsigned olo = __shfl_xor(lo, m, 64);
        unsigned long long o = ((unsigned long long)ohi << 32) | olo;
        if (o > best) best = o;
    }
    __shared__ unsigned long long sb[16];
    int lane = threadIdx.x & 63, w = threadIdx.x >> 6;
    if (lane == 0) sb[w] = best;
    __syncthreads();
    if (threadIdx.x == 0) {
        unsigned long long b = sb[0];
        #pragma unroll
        for (int w2 = 1; w2 < 16; ++w2) if (sb[w2] > b) b = sb[w2];
        out[0] = (float)(~(unsigned)(b & 0xFFFFFFFFull));
        out[1] = sqrtf(__uint_as_float((unsigned)(b >> 32)));
    }
}

// ---------------------------------------------------------------------------
extern "C" void kernel_launch(void* const* d_in, const int* in_sizes, int n_in,
                              void* d_out, int out_size, void* d_ws, size_t ws_size,
                              hipStream_t stream)
{
    const float* A = (const float*)d_in[0];
    const float* B = (const float*)d_in[1];
    const int N = in_sizes[0] / K_DIM;           // 50000
    const int M = in_sizes[1] / K_DIM;           // 5000
    const int ntile = (N + BM - 1) / BM;         // 391
    const int njt   = (M + BN - 1) / BN;         // 40
    const int Npad = ntile * BM, Mpad = njt * BN;

    char* ws = (char*)d_ws;
    float*    na   = (float*)ws;                     // Npad
    float*    nb   = na + Npad;                      // Mpad
    unsigned* vmin = (unsigned*)(nb + Mpad);         // Npad
    size_t off0 = ((size_t)(Npad + Mpad + Npad) * 4 + 255) & ~(size_t)255;
    ushort* AhW = (ushort*)(ws + off0);              // Npad*512 f16
    ushort* BhW = AhW + (size_t)Npad * K_DIM;        // Mpad*512 f16
    size_t off1 = (off0 + ((size_t)Npad + Mpad) * K_DIM * 2 + 255) & ~(size_t)255;
    unsigned* maxout = (unsigned*)(ws + off1);
    int* counter = (int*)(maxout + 1);
    int* list    = counter + 1;                      // LIST_MAX ints
    unsigned* vminx = (unsigned*)(list + LIST_MAX);  // LIST_MAX uints
    size_t need = off1 + 16 + (size_t)LIST_MAX * 8;

    float* out = (float*)d_out;

    int waves = Npad + Mpad;
    hipLaunchKernelGGL(norms_init_kernel, dim3((waves + 3) / 4), dim3(256), 0, stream,
                       A, B, na, nb, vmin, vminx, counter, maxout, N, M, Npad, Mpad);

    if (ws_size >= need) {
        hipLaunchKernelGGL(preconvert_f16_kernel, dim3((Npad * 64 + 255) / 256), dim3(256), 0, stream,
                           A, AhW, N, Npad);
        hipLaunchKernelGGL(preconvert_f16_kernel, dim3((Mpad * 64 + 255) / 256), dim3(256), 0, stream,
                           B, BhW, M, Mpad);
        hipLaunchKernelGGL(gemm_min_f16, dim3(JCHUNKS, ntile), dim3(256), 0, stream,
                           AhW, BhW, na, nb, vmin, N, njt);
    } else {
        hipLaunchKernelGGL(gemm_min_fused, dim3(JCHUNKS, ntile), dim3(256), 0, stream,
                           A, B, na, nb, vmin, N, M, njt);
    }

    hipLaunchKernelGGL(maxred_kernel, dim3(128), dim3(256), 0, stream,
                       vmin, maxout, N);
    hipLaunchKernelGGL(cand_kernel, dim3((N + 255) / 256), dim3(256), 0, stream,
                       vmin, maxout, counter, list, N);
    hipLaunchKernelGGL(refine_kernel, dim3(REF_GRID), dim3(256), 0, stream,
                       A, B, na, nb, counter, list, vminx, M);
    hipLaunchKernelGGL(final_kernel, dim3(1), dim3(1024), 0, stream,
                       counter, list, vminx, out);
}

// Round 19
// 442.704 us; speedup vs baseline: 2.3498x; 2.3498x over previous
//
// Round 19: NO-LDS, NO-BARRIER all-register GEMM. A and B fragments both load
// directly from the preconverted L2-resident f16 images into statically-named
// register double-buffers (x2-unrolled loop, rule #20 safe). Zero __shared__,
// zero __syncthreads -> the ~450cyc/step barrier-lockstep term (invariant
// across r12-r17) is structurally deleted; waves free-run with compiler vmcnt.
// launch_bounds(256,3): ~150 VGPR live set < 170 cap (r18 spilled at cap 128).
// Filter+refine machinery unchanged from r17.
#include <hip/hip_runtime.h>
#include <cstdint>
#include <cstddef>

#define K_DIM 512
#define BM 128
#define BN 128
#define BK 32
#define JCHUNKS 8
#define LIST_MAX 4096
#define WINDOW 4.0f
#define NSLICE 32
#define REF_GRID 1024

typedef __attribute__((ext_vector_type(8))) _Float16 f16x8;
typedef __attribute__((ext_vector_type(8))) __bf16 bf16x8;
typedef __attribute__((ext_vector_type(8))) short short8;
typedef __attribute__((ext_vector_type(4))) float f32x4;

// ---------------------------------------------------------------------------
// Kernel 0: row norms + init vmin/vminx/counter/maxout.
// ---------------------------------------------------------------------------
__global__ __launch_bounds__(256) void norms_init_kernel(
    const float* __restrict__ A, const float* __restrict__ B,
    float* __restrict__ na, float* __restrict__ nb,
    unsigned* __restrict__ vmin, unsigned* __restrict__ vminx,
    int* __restrict__ counter, unsigned* __restrict__ maxout,
    int N, int M, int Npad, int Mpad)
{
    if (blockIdx.x == 0) {                       // one-time small-state init
        for (int c = threadIdx.x; c < LIST_MAX; c += 256)
            vminx[c] = 0x7f800000u;
        if (threadIdx.x == 0) { *counter = 0; *maxout = 0u; }
    }
    int w = (int)((blockIdx.x * blockDim.x + threadIdx.x) >> 6);
    int lane = threadIdx.x & 63;
    if (w >= Npad + Mpad) return;
    if (w < Npad) {
        float s = 0.f;
        if (w < N) {
            const float* src = A + (size_t)w * K_DIM + lane * 8;
            float4 v0 = *(const float4*)src;
            float4 v1 = *(const float4*)(src + 4);
            s = v0.x*v0.x + v0.y*v0.y + v0.z*v0.z + v0.w*v0.w
              + v1.x*v1.x + v1.y*v1.y + v1.z*v1.z + v1.w*v1.w;
            #pragma unroll
            for (int m = 1; m < 64; m <<= 1) s += __shfl_xor(s, m, 64);
        }
        if (lane == 0) { na[w] = s; vmin[w] = 0x7f800000u; }
    } else {
        int j = w - Npad;
        float s = __builtin_inff();   // padded centers never win the min
        if (j < M) {
            const float* src = B + (size_t)j * K_DIM + lane * 8;
            float4 v0 = *(const float4*)src;
            float4 v1 = *(const float4*)(src + 4);
            s = v0.x*v0.x + v0.y*v0.y + v0.z*v0.z + v0.w*v0.w
              + v1.x*v1.x + v1.y*v1.y + v1.z*v1.z + v1.w*v1.w;
            #pragma unroll
            for (int m = 1; m < 64; m <<= 1) s += __shfl_xor(s, m, 64);
        }
        if (lane == 0) nb[j] = s;
    }
}

// ---------------------------------------------------------------------------
// Kernel 1: preconvert fp32 -> fp16 in the per-(tile,kt) image layout
// [tile][kt][g][m][8], 128-row tiles.
// ---------------------------------------------------------------------------
__global__ __launch_bounds__(256) void preconvert_f16_kernel(
    const float* __restrict__ src, ushort* __restrict__ outW,
    int realRows, int padRows)
{
    int c = blockIdx.x * 256 + threadIdx.x;            // chunk id
    int total = padRows * (K_DIM / 8);
    if (c >= total) return;
    int m    = c & (BM - 1);
    int g    = (c >> 7) & 3;
    int kt   = (c >> 9) & 15;
    int tile = c >> 13;
    int row  = tile * BM + m;
    int k    = kt * BK + g * 8;
    float f[8];
    if (row < realRows) {
        float4 x0 = *(const float4*)(src + (size_t)row * K_DIM + k);
        float4 x1 = *(const float4*)(src + (size_t)row * K_DIM + k + 4);
        f[0]=x0.x; f[1]=x0.y; f[2]=x0.z; f[3]=x0.w;
        f[4]=x1.x; f[5]=x1.y; f[6]=x1.z; f[7]=x1.w;
    } else {
        #pragma unroll
        for (int q = 0; q < 8; ++q) f[q] = 0.f;
    }
    f16x8 h;
    #pragma unroll
    for (int q = 0; q < 8; ++q) h[q] = (_Float16)f[q];   // RTN
    *(f16x8*)(outW + (size_t)c * 8) = h;
}

// ---------------------------------------------------------------------------
// Kernel 2: 1-pass fp16 MFMA GEMM + fused row-min (approximate filter).
// ALL-REGISTER: A and B frags read directly from the L2-resident images into
// register dbufs aA/aB, bA/bB (statically named). No LDS, no barriers.
// 128x128 tile, 4 waves (2x2), wave tile 64x64, 16 MFMA/wave/step.
// ---------------------------------------------------------------------------
__global__ __launch_bounds__(256, 3) void gemm_min_f16(
    const ushort* __restrict__ AhW, const ushort* __restrict__ BhW,
    const float* __restrict__ na, const float* __restrict__ nb,
    unsigned* __restrict__ vmin, int N, int njt)
{
    const int tid  = threadIdx.x;
    const int lane = tid & 63;
    const int wave = tid >> 6;
    const int wr = (wave >> 1) * 64;
    const int wc = (wave & 1) * 64;
    const int tr = lane & 15;
    const int tg = lane >> 4;
    const int tile = blockIdx.y;          // A-tile (slow axis)

    const int per = (njt + JCHUNKS - 1) / JCHUNKS;
    const int jt_begin = min((int)blockIdx.x * per, njt);   // chunk = fast axis
    const int jt_end   = min(jt_begin + per, njt);

    float localmin[16];
    #pragma unroll
    for (int u = 0; u < 16; ++u) localmin[u] = __builtin_inff();

    // per-lane fragment base offsets within a (row-tile,kt) panel (ushorts)
    const size_t aoff = ((size_t)tg * 128 + wr + tr) * 8;
    const size_t boff = ((size_t)tg * 128 + wc + tr) * 8;

    auto LOAD_A = [&](f16x8* dst, int t) {      // dst: NAMED register array
        const int kt = t & 15;
        const ushort* sA = AhW + ((size_t)tile * 16 + kt) * 4096 + aoff;
        #pragma unroll
        for (int fi = 0; fi < 4; ++fi)
            dst[fi] = *(const f16x8*)(sA + (size_t)fi * 128);
    };
    auto LOAD_B = [&](f16x8* dst, int t) {
        const int jt = jt_begin + (t >> 4);
        const int kt = t & 15;
        const ushort* sB = BhW + ((size_t)jt * 16 + kt) * 4096 + boff;
        #pragma unroll
        for (int fj = 0; fj < 4; ++fj)
            dst[fj] = *(const f16x8*)(sB + (size_t)fj * 128);
    };

    if (jt_begin < jt_end) {
        const int T = (jt_end - jt_begin) * 16;   // multiple of 16 (even)

        f16x8 aA[4], aB[4], bA[4], bB[4];         // register double buffers
        LOAD_A(aA, 0);
        LOAD_B(bA, 0);

        f32x4 acc[4][4];
        #pragma unroll
        for (int fi = 0; fi < 4; ++fi)
            #pragma unroll
            for (int fj = 0; fj < 4; ++fj) acc[fi][fj] = (f32x4)0.f;

        for (int t = 0; t < T; t += 2) {
            // ----- even step t: consume aA/bA, prefetch (t+1) into aB/bB -----
            {
                LOAD_A(aB, t + 1);                // t+1 < T (T even)
                LOAD_B(bB, t + 1);
                #pragma unroll
                for (int fi = 0; fi < 4; ++fi)
                    #pragma unroll
                    for (int fj = 0; fj < 4; ++fj)
                        acc[fi][fj] = __builtin_amdgcn_mfma_f32_16x16x32_f16(
                            aA[fi], bA[fj], acc[fi][fj], 0, 0, 0);
                // t even -> no fold here
            }
            // ----- odd step t+1: consume aB/bB, prefetch (t+2) into aA/bA ---
            {
                if (t + 2 < T) {
                    LOAD_A(aA, t + 2);
                    LOAD_B(bA, t + 2);
                }
                #pragma unroll
                for (int fi = 0; fi < 4; ++fi)
                    #pragma unroll
                    for (int fj = 0; fj < 4; ++fj)
                        acc[fi][fj] = __builtin_amdgcn_mfma_f32_16x16x32_f16(
                            aB[fi], bB[fj], acc[fi][fj], 0, 0, 0);

                if (((t + 1) & 15) == 15) {       // end of a jt: fold row-min
                    const int jt = jt_begin + ((t + 1) >> 4);
                    #pragma unroll
                    for (int fj = 0; fj < 4; ++fj) {
                        int j = jt * BN + wc + fj * 16 + tr;
                        float nbv = nb[j];        // padded with +inf
                        #pragma unroll
                        for (int fi = 0; fi < 4; ++fi)
                            #pragma unroll
                            for (int r = 0; r < 4; ++r) {
                                float s = fmaf(-2.f, acc[fi][fj][r], nbv);
                                localmin[fi * 4 + r] = fminf(localmin[fi * 4 + r], s);
                            }
                    }
                    #pragma unroll
                    for (int fi = 0; fi < 4; ++fi)
                        #pragma unroll
                        for (int fj = 0; fj < 4; ++fj) acc[fi][fj] = (f32x4)0.f;
                }
            }
        }
    }

    #pragma unroll
    for (int u = 0; u < 16; ++u) {
        float v = localmin[u];
        #pragma unroll
        for (int m = 1; m < 16; m <<= 1) v = fminf(v, __shfl_xor(v, m, 64));
        localmin[u] = v;
    }
    if (tr == 0) {
        #pragma unroll
        for (int fi = 0; fi < 4; ++fi)
            #pragma unroll
            for (int r = 0; r < 4; ++r) {
                int i = tile * BM + wr + fi * 16 + tg * 4 + r;
                if (i < N) {
                    float v = fmaxf(na[i] + localmin[fi * 4 + r], 0.f);
                    atomicMin(&vmin[i], __float_as_uint(v));
                }
            }
    }
}

// ---------------------------------------------------------------------------
// Kernel 2b: fallback (ws too small) — bf16 3-pass, 128x128, in-staging conv.
// ---------------------------------------------------------------------------
__global__ __launch_bounds__(256, 2) void gemm_min_fused(
    const float* __restrict__ A, const float* __restrict__ B,
    const float* __restrict__ na, const float* __restrict__ nb,
    unsigned* __restrict__ vmin, int N, int M, int njt)
{
    __shared__ ushort Ah[4096], Al[4096], Bh[4096], Bl[4096];

    const int tid  = threadIdx.x;
    const int lane = tid & 63;
    const int wave = tid >> 6;
    const int wr = (wave >> 1) * 64;
    const int wc = (wave & 1) * 64;
    const int tr = lane & 15;
    const int tg = lane >> 4;
    const int i0 = blockIdx.y * BM;

    const int sm = tid & 127;
    const int sh = tid >> 7;

    const int per = (njt + JCHUNKS - 1) / JCHUNKS;
    const int jt_begin = min((int)blockIdx.x * per, njt);
    const int jt_end   = min(jt_begin + per, njt);

    float localmin[16];
    #pragma unroll
    for (int u = 0; u < 16; ++u) localmin[u] = __builtin_inff();

    for (int jt = jt_begin; jt < jt_end; ++jt) {
        const int j0 = jt * BN;
        f32x4 acc[4][4];
        #pragma unroll
        for (int fi = 0; fi < 4; ++fi)
            #pragma unroll
            for (int fj = 0; fj < 4; ++fj) acc[fi][fj] = (f32x4)0.f;

        for (int kt = 0; kt < K_DIM / BK; ++kt) {
            const int k0 = kt * BK + sh * 16;
            {
                float f[16];
                int gi = i0 + sm;
                if (gi < N) {
                    const float* p = A + (size_t)gi * K_DIM + k0;
                    #pragma unroll
                    for (int q = 0; q < 4; ++q) {
                        float4 x = *(const float4*)(p + q * 4);
                        f[q*4+0]=x.x; f[q*4+1]=x.y; f[q*4+2]=x.z; f[q*4+3]=x.w;
                    }
                } else {
                    #pragma unroll
                    for (int q = 0; q < 16; ++q) f[q] = 0.f;
                }
                short8 h0, h1, l0, l1;
                #pragma unroll
                for (int q = 0; q < 8; ++q) {
                    uint u = __float_as_uint(f[q]);
                    h0[q] = (short)(u >> 16);
                    float lo = f[q] - __uint_as_float(u & 0xffff0000u);
                    l0[q] = (short)(__float_as_uint(lo) >> 16);
                }
                #pragma unroll
                for (int q = 0; q < 8; ++q) {
                    uint u = __float_as_uint(f[8+q]);
                    h1[q] = (short)(u >> 16);
                    float lo = f[8+q] - __uint_as_float(u & 0xffff0000u);
                    l1[q] = (short)(__float_as_uint(lo) >> 16);
                }
                int g0 = sh * 2;
                *(short8*)(Ah + (g0 * 128 + sm) * 8)       = h0;
                *(short8*)(Ah + ((g0 + 1) * 128 + sm) * 8) = h1;
                *(short8*)(Al + (g0 * 128 + sm) * 8)       = l0;
                *(short8*)(Al + ((g0 + 1) * 128 + sm) * 8) = l1;
            }
            {
                float f[16];
                int gj = j0 + sm;
                if (gj < M) {
                    const float* p = B + (size_t)gj * K_DIM + k0;
                    #pragma unroll
                    for (int q = 0; q < 4; ++q) {
                        float4 x = *(const float4*)(p + q * 4);
                        f[q*4+0]=x.x; f[q*4+1]=x.y; f[q*4+2]=x.z; f[q*4+3]=x.w;
                    }
                } else {
                    #pragma unroll
                    for (int q = 0; q < 16; ++q) f[q] = 0.f;
                }
                short8 h0, h1, l0, l1;
                #pragma unroll
                for (int q = 0; q < 8; ++q) {
                    uint u = __float_as_uint(f[q]);
                    h0[q] = (short)(u >> 16);
                    float lo = f[q] - __uint_as_float(u & 0xffff0000u);
                    l0[q] = (short)(__float_as_uint(lo) >> 16);
                }
                #pragma unroll
                for (int q = 0; q < 8; ++q) {
                    uint u = __float_as_uint(f[8+q]);
                    h1[q] = (short)(u >> 16);
                    float lo = f[8+q] - __uint_as_float(u & 0xffff0000u);
                    l1[q] = (short)(__float_as_uint(lo) >> 16);
                }
                int g0 = sh * 2;
                *(short8*)(Bh + (g0 * 128 + sm) * 8)       = h0;
                *(short8*)(Bh + ((g0 + 1) * 128 + sm) * 8) = h1;
                *(short8*)(Bl + (g0 * 128 + sm) * 8)       = l0;
                *(short8*)(Bl + ((g0 + 1) * 128 + sm) * 8) = l1;
            }
            __syncthreads();

            bf16x8 a_h[4], a_l[4], b_h[4], b_l[4];
            #pragma unroll
            for (int fi = 0; fi < 4; ++fi) {
                int ra = (tg * 128 + wr + fi * 16 + tr) * 8;
                a_h[fi] = *(const bf16x8*)(Ah + ra);
                a_l[fi] = *(const bf16x8*)(Al + ra);
            }
            #pragma unroll
            for (int fj = 0; fj < 4; ++fj) {
                int rb = (tg * 128 + wc + fj * 16 + tr) * 8;
                b_h[fj] = *(const bf16x8*)(Bh + rb);
                b_l[fj] = *(const bf16x8*)(Bl + rb);
            }
            #pragma unroll
            for (int fi = 0; fi < 4; ++fi)
                #pragma unroll
                for (int fj = 0; fj < 4; ++fj) {
                    acc[fi][fj] = __builtin_amdgcn_mfma_f32_16x16x32_bf16(a_h[fi], b_h[fj], acc[fi][fj], 0, 0, 0);
                    acc[fi][fj] = __builtin_amdgcn_mfma_f32_16x16x32_bf16(a_h[fi], b_l[fj], acc[fi][fj], 0, 0, 0);
                    acc[fi][fj] = __builtin_amdgcn_mfma_f32_16x16x32_bf16(a_l[fi], b_h[fj], acc[fi][fj], 0, 0, 0);
                }
            __syncthreads();
        }

        #pragma unroll
        for (int fj = 0; fj < 4; ++fj) {
            int j = j0 + wc + fj * 16 + tr;
            float nbv = nb[j];
            #pragma unroll
            for (int fi = 0; fi < 4; ++fi)
                #pragma unroll
                for (int r = 0; r < 4; ++r) {
                    float s = fmaf(-2.f, acc[fi][fj][r], nbv);
                    localmin[fi * 4 + r] = fminf(localmin[fi * 4 + r], s);
                }
        }
    }

    #pragma unroll
    for (int u = 0; u < 16; ++u) {
        float v = localmin[u];
        #pragma unroll
        for (int m = 1; m < 16; m <<= 1) v = fminf(v, __shfl_xor(v, m, 64));
        localmin[u] = v;
    }
    if (tr == 0) {
        #pragma unroll
        for (int fi = 0; fi < 4; ++fi)
            #pragma unroll
            for (int r = 0; r < 4; ++r) {
                int i = i0 + wr + fi * 16 + tg * 4 + r;
                if (i < N) {
                    float v = fmaxf(na[i] + localmin[fi * 4 + r], 0.f);
                    atomicMin(&vmin[i], __float_as_uint(v));
                }
            }
    }
}

// ---------------------------------------------------------------------------
// Kernel 3: parallel max of vmin (128 blocks, device atomicMax).
// ---------------------------------------------------------------------------
__global__ __launch_bounds__(256) void maxred_kernel(
    const unsigned* __restrict__ vmin, unsigned* __restrict__ maxout, int N)
{
    unsigned best = 0u;
    for (int i = blockIdx.x * 256 + threadIdx.x; i < N; i += gridDim.x * 256) {
        unsigned v = vmin[i];
        if (v > best) best = v;
    }
    #pragma unroll
    for (int m = 1; m < 64; m <<= 1) {
        unsigned o = __shfl_xor(best, m, 64);
        if (o > best) best = o;
    }
    __shared__ unsigned sb[4];
    int lane = threadIdx.x & 63, w = threadIdx.x >> 6;
    if (lane == 0) sb[w] = best;
    __syncthreads();
    if (threadIdx.x == 0) {
        unsigned b = sb[0];
        #pragma unroll
        for (int w2 = 1; w2 < 4; ++w2) if (sb[w2] > b) b = sb[w2];
        atomicMax(maxout, b);
    }
}

// ---------------------------------------------------------------------------
// Kernel 4: collect candidate rows within WINDOW of the approx max.
// ---------------------------------------------------------------------------
__global__ __launch_bounds__(256) void cand_kernel(
    const unsigned* __restrict__ vmin, const unsigned* __restrict__ maxout,
    int* __restrict__ counter, int* __restrict__ list, int N)
{
    int i = blockIdx.x * 256 + threadIdx.x;
    if (i >= N) return;
    float thr = __uint_as_float(*maxout) - WINDOW;
    if (__uint_as_float(vmin[i]) >= thr) {
        int p = atomicAdd(counter, 1);
        if (p < LIST_MAX) list[p] = i;
    }
}

// ---------------------------------------------------------------------------
// Kernel 5: exact fp32 refinement, parallel over (candidate, j-slice).
// ---------------------------------------------------------------------------
__global__ __launch_bounds__(256) void refine_kernel(
    const float* __restrict__ A, const float* __restrict__ B,
    const float* __restrict__ na, const float* __restrict__ nb,
    const int* __restrict__ counter, const int* __restrict__ list,
    unsigned* __restrict__ vminx, int M)
{
    __shared__ float arow[K_DIM];
    __shared__ float sred[4];
    const int tid = threadIdx.x, lane = tid & 63, w = tid >> 6;
    int cnt = *counter;
    if (cnt > LIST_MAX) cnt = LIST_MAX;
    const int slice = (M + NSLICE - 1) / NSLICE;   // ~157

    for (int idx = blockIdx.x; idx < cnt * NSLICE; idx += gridDim.x) {
        const int c = idx / NSLICE;
        const int s = idx % NSLICE;
        const int i = list[c];
        const int j0 = s * slice;
        const int j1 = min(j0 + slice, M);

        __syncthreads();                           // protect arow/sred reuse
        for (int k = tid; k < K_DIM; k += 256)
            arow[k] = A[(size_t)i * K_DIM + k];
        __syncthreads();

        float4 a0 = *(const float4*)&arow[lane * 8];
        float4 a1 = *(const float4*)&arow[lane * 8 + 4];
        float lmin = __builtin_inff();
        for (int j = j0 + w; j < j1; j += 4) {     // wave w takes every 4th j
            const float* br = B + (size_t)j * K_DIM + lane * 8;
            float4 x0 = *(const float4*)br;
            float4 x1 = *(const float4*)(br + 4);
            float d = x0.x*a0.x + x0.y*a0.y + x0.z*a0.z + x0.w*a0.w
                    + x1.x*a1.x + x1.y*a1.y + x1.z*a1.z + x1.w*a1.w;
            #pragma unroll
            for (int m = 1; m < 64; m <<= 1) d += __shfl_xor(d, m, 64);
            float y = fmaf(-2.f, d, nb[j]);
            lmin = fminf(lmin, y);
        }
        if (lane == 0) sred[w] = lmin;
        __syncthreads();
        if (tid == 0) {
            float m2 = fminf(fminf(sred[0], sred[1]), fminf(sred[2], sred[3]));
            float v = fmaxf(na[i] + m2, 0.f);
            atomicMin(&vminx[c], __float_as_uint(v));
        }
    }
}

// ---------------------------------------------------------------------------
// Kernel 6: final — packed max over candidates' exact values, sqrt, write out.
// ---------------------------------------------------------------------------
__global__ __launch_bounds__(1024) void final_kernel(
    const int* __restrict__ counter, const int* __restrict__ list,
    const unsigned* __restrict__ vminx, float* __restrict__ out)
{
    int cnt = *counter;
    if (cnt > LIST_MAX) cnt = LIST_MAX;
    unsigned long long best = 0ull;
    for (int c = threadIdx.x; c < cnt; c += 1024) {
        unsigned long long p =
            ((unsigned long long)vminx[c] << 32) | (unsigned)(~list[c]);
        if (p > best) best = p;
    }
    #pragma unroll
    for (int m = 1; m < 64; m <<= 1) {
        unsigned hi = (unsigned)(best >> 32), lo = (unsigned)best;
        unsigned ohi = __shfl_xor(hi, m, 64);
        unsigned olo = __shfl_xor(lo, m, 64);
        unsigned long long o = ((unsigned long long)ohi << 32) | olo;
        if (o > best) best = o;
    }
    __shared__ unsigned long long sb[16];
    int lane = threadIdx.x & 63, w = threadIdx.x >> 6;
    if (lane == 0) sb[w] = best;
    __syncthreads();
    if (threadIdx.x == 0) {
        unsigned long long b = sb[0];
        #pragma unroll
        for (int w2 = 1; w2 < 16; ++w2) if (sb[w2] > b) b = sb[w2];
        out[0] = (float)(~(unsigned)(b & 0xFFFFFFFFull));
        out[1] = sqrtf(__uint_as_float((unsigned)(b >> 32)));
    }
}

// ---------------------------------------------------------------------------
extern "C" void kernel_launch(void* const* d_in, const int* in_sizes, int n_in,
                              void* d_out, int out_size, void* d_ws, size_t ws_size,
                              hipStream_t stream)
{
    const float* A = (const float*)d_in[0];
    const float* B = (const float*)d_in[1];
    const int N = in_sizes[0] / K_DIM;           // 50000
    const int M = in_sizes[1] / K_DIM;           // 5000
    const int ntile = (N + BM - 1) / BM;         // 391
    const int njt   = (M + BN - 1) / BN;         // 40
    const int Npad = ntile * BM, Mpad = njt * BN;

    char* ws = (char*)d_ws;
    float*    na   = (float*)ws;                     // Npad
    float*    nb   = na + Npad;                      // Mpad
    unsigned* vmin = (unsigned*)(nb + Mpad);         // Npad
    size_t off0 = ((size_t)(Npad + Mpad + Npad) * 4 + 255) & ~(size_t)255;
    ushort* AhW = (ushort*)(ws + off0);              // Npad*512 f16
    ushort* BhW = AhW + (size_t)Npad * K_DIM;        // Mpad*512 f16
    size_t off1 = (off0 + ((size_t)Npad + Mpad) * K_DIM * 2 + 255) & ~(size_t)255;
    unsigned* maxout = (unsigned*)(ws + off1);
    int* counter = (int*)(maxout + 1);
    int* list    = counter + 1;                      // LIST_MAX ints
    unsigned* vminx = (unsigned*)(list + LIST_MAX);  // LIST_MAX uints
    size_t need = off1 + 16 + (size_t)LIST_MAX * 8;

    float* out = (float*)d_out;

    int waves = Npad + Mpad;
    hipLaunchKernelGGL(norms_init_kernel, dim3((waves + 3) / 4), dim3(256), 0, stream,
                       A, B, na, nb, vmin, vminx, counter, maxout, N, M, Npad, Mpad);

    if (ws_size >= need) {
        hipLaunchKernelGGL(preconvert_f16_kernel, dim3((Npad * 64 + 255) / 256), dim3(256), 0, stream,
                           A, AhW, N, Npad);
        hipLaunchKernelGGL(preconvert_f16_kernel, dim3((Mpad * 64 + 255) / 256), dim3(256), 0, stream,
                           B, BhW, M, Mpad);
        hipLaunchKernelGGL(gemm_min_f16, dim3(JCHUNKS, ntile), dim3(256), 0, stream,
                           AhW, BhW, na, nb, vmin, N, njt);
    } else {
        hipLaunchKernelGGL(gemm_min_fused, dim3(JCHUNKS, ntile), dim3(256), 0, stream,
                           A, B, na, nb, vmin, N, M, njt);
    }

    hipLaunchKernelGGL(maxred_kernel, dim3(128), dim3(256), 0, stream,
                       vmin, maxout, N);
    hipLaunchKernelGGL(cand_kernel, dim3((N + 255) / 256), dim3(256), 0, stream,
                       vmin, maxout, counter, list, N);
    hipLaunchKernelGGL(refine_kernel, dim3(REF_GRID), dim3(256), 0, stream,
                       A, B, na, nb, counter, list, vminx, M);
    hipLaunchKernelGGL(final_kernel, dim3(1), dim3(1024), 0, stream,
                       counter, list, vminx, out);
}

// Round 20
// 398.814 us; speedup vs baseline: 2.6084x; 1.1101x over previous
//
// Round 20 (FINAL COMPOSition): r12's gemm — the best measured across all 8
// structural variants (LDS A+B 32KB, issue-early 2-phase, 309us) — combined
// with r15/r17's reduction-side improvements (parallel maxred, init folded
// into norms). Ledger: r12 309 | r17 317 | r15 324 | r14 342 | r19 365 |
// r13 376 | r6/r10 777+ | r18 957. 2-phase 128^2 LDS pipeline = family optimum.
#include <hip/hip_runtime.h>
#include <cstdint>
#include <cstddef>

#define K_DIM 512
#define BM 128
#define BN 128
#define BK 32
#define JCHUNKS 8
#define LIST_MAX 4096
#define WINDOW 4.0f
#define NSLICE 32
#define REF_GRID 1024

typedef __attribute__((ext_vector_type(8))) _Float16 f16x8;
typedef __attribute__((ext_vector_type(8))) __bf16 bf16x8;
typedef __attribute__((ext_vector_type(8))) short short8;
typedef __attribute__((ext_vector_type(4))) float f32x4;

// ---------------------------------------------------------------------------
// Kernel 0: row norms + init vmin/vminx/counter/maxout.
// ---------------------------------------------------------------------------
__global__ __launch_bounds__(256) void norms_init_kernel(
    const float* __restrict__ A, const float* __restrict__ B,
    float* __restrict__ na, float* __restrict__ nb,
    unsigned* __restrict__ vmin, unsigned* __restrict__ vminx,
    int* __restrict__ counter, unsigned* __restrict__ maxout,
    int N, int M, int Npad, int Mpad)
{
    if (blockIdx.x == 0) {                       // one-time small-state init
        for (int c = threadIdx.x; c < LIST_MAX; c += 256)
            vminx[c] = 0x7f800000u;
        if (threadIdx.x == 0) { *counter = 0; *maxout = 0u; }
    }
    int w = (int)((blockIdx.x * blockDim.x + threadIdx.x) >> 6);
    int lane = threadIdx.x & 63;
    if (w >= Npad + Mpad) return;
    if (w < Npad) {
        float s = 0.f;
        if (w < N) {
            const float* src = A + (size_t)w * K_DIM + lane * 8;
            float4 v0 = *(const float4*)src;
            float4 v1 = *(const float4*)(src + 4);
            s = v0.x*v0.x + v0.y*v0.y + v0.z*v0.z + v0.w*v0.w
              + v1.x*v1.x + v1.y*v1.y + v1.z*v1.z + v1.w*v1.w;
            #pragma unroll
            for (int m = 1; m < 64; m <<= 1) s += __shfl_xor(s, m, 64);
        }
        if (lane == 0) { na[w] = s; vmin[w] = 0x7f800000u; }
    } else {
        int j = w - Npad;
        float s = __builtin_inff();   // padded centers never win the min
        if (j < M) {
            const float* src = B + (size_t)j * K_DIM + lane * 8;
            float4 v0 = *(const float4*)src;
            float4 v1 = *(const float4*)(src + 4);
            s = v0.x*v0.x + v0.y*v0.y + v0.z*v0.z + v0.w*v0.w
              + v1.x*v1.x + v1.y*v1.y + v1.z*v1.z + v1.w*v1.w;
            #pragma unroll
            for (int m = 1; m < 64; m <<= 1) s += __shfl_xor(s, m, 64);
        }
        if (lane == 0) nb[j] = s;
    }
}

// ---------------------------------------------------------------------------
// Kernel 1: preconvert fp32 -> fp16 in the per-(tile,kt) image layout
// [tile][kt][g][m][8], 128-row tiles (the GEMM's linear LDS image).
// ---------------------------------------------------------------------------
__global__ __launch_bounds__(256) void preconvert_f16_kernel(
    const float* __restrict__ src, ushort* __restrict__ outW,
    int realRows, int padRows)
{
    int c = blockIdx.x * 256 + threadIdx.x;            // chunk id
    int total = padRows * (K_DIM / 8);
    if (c >= total) return;
    int m    = c & (BM - 1);
    int g    = (c >> 7) & 3;
    int kt   = (c >> 9) & 15;
    int tile = c >> 13;
    int row  = tile * BM + m;
    int k    = kt * BK + g * 8;
    float f[8];
    if (row < realRows) {
        float4 x0 = *(const float4*)(src + (size_t)row * K_DIM + k);
        float4 x1 = *(const float4*)(src + (size_t)row * K_DIM + k + 4);
        f[0]=x0.x; f[1]=x0.y; f[2]=x0.z; f[3]=x0.w;
        f[4]=x1.x; f[5]=x1.y; f[6]=x1.z; f[7]=x1.w;
    } else {
        #pragma unroll
        for (int q = 0; q < 8; ++q) f[q] = 0.f;
    }
    f16x8 h;
    #pragma unroll
    for (int q = 0; q < 8; ++q) h[q] = (_Float16)f[q];   // RTN
    *(f16x8*)(outW + (size_t)c * 8) = h;
}

// ---------------------------------------------------------------------------
// Kernel 2: 1-pass fp16 MFMA GEMM + fused row-min (the r12 configuration —
// best measured). A and B both staged via global_load_lds into 32KB dbuf LDS;
// issue-early STAGE(t+1) before compute(t); one __syncthreads per t.
// 128x128 tile, 4 waves (2x2), wave tile 64x64, 16 MFMA/wave/step.
// ---------------------------------------------------------------------------
__global__ __launch_bounds__(256, 4) void gemm_min_f16(
    const ushort* __restrict__ AhW, const ushort* __restrict__ BhW,
    const float* __restrict__ na, const float* __restrict__ nb,
    unsigned* __restrict__ vmin, int N, int njt)
{
    __shared__ ushort Ah[2][4096], Bh[2][4096];   // 32 KB

    const int tid  = threadIdx.x;
    const int lane = tid & 63;
    const int wave = tid >> 6;
    const int wr = (wave >> 1) * 64;
    const int wc = (wave & 1) * 64;
    const int tr = lane & 15;
    const int tg = lane >> 4;
    const int tile = blockIdx.y;          // A-tile (slow axis)

    const int per = (njt + JCHUNKS - 1) / JCHUNKS;
    const int jt_begin = min((int)blockIdx.x * per, njt);   // chunk = fast axis
    const int jt_end   = min(jt_begin + per, njt);

    float localmin[16];
    #pragma unroll
    for (int u = 0; u < 16; ++u) localmin[u] = __builtin_inff();

    auto STAGE = [&](int buf, int t) {
        const int jt = jt_begin + (t >> 4);
        const int kt = t & 15;
        const ushort* sA = AhW + ((size_t)tile * 16 + kt) * 4096;
        const ushort* sB = BhW + ((size_t)jt   * 16 + kt) * 4096;
        #pragma unroll
        for (int q = 0; q < 2; ++q) {
            int gi = (q * 256 + tid) * 8;          // per-lane global offset
            int li = (q * 256 + wave * 64) * 8;    // wave-uniform LDS base
            __builtin_amdgcn_global_load_lds(
                (const __attribute__((address_space(1))) void*)(sA + gi),
                (__attribute__((address_space(3))) void*)(&Ah[buf][li]), 16, 0, 0);
            __builtin_amdgcn_global_load_lds(
                (const __attribute__((address_space(1))) void*)(sB + gi),
                (__attribute__((address_space(3))) void*)(&Bh[buf][li]), 16, 0, 0);
        }
    };

    if (jt_begin < jt_end) {
        const int T = (jt_end - jt_begin) * 16;

        STAGE(0, 0);
        __syncthreads();           // drain prologue loads
        int cur = 0;

        f32x4 acc[4][4];
        #pragma unroll
        for (int fi = 0; fi < 4; ++fi)
            #pragma unroll
            for (int fj = 0; fj < 4; ++fj) acc[fi][fj] = (f32x4)0.f;

        for (int t = 0; t < T; ++t) {
            if (t + 1 < T) STAGE(cur ^ 1, t + 1);   // issue-early prefetch

            f16x8 a_[4], b_[4];
            #pragma unroll
            for (int fi = 0; fi < 4; ++fi) {
                int ra = (tg * 128 + wr + fi * 16 + tr) * 8;
                a_[fi] = *(const f16x8*)(&Ah[cur][ra]);
            }
            #pragma unroll
            for (int fj = 0; fj < 4; ++fj) {
                int rb = (tg * 128 + wc + fj * 16 + tr) * 8;
                b_[fj] = *(const f16x8*)(&Bh[cur][rb]);
            }
            #pragma unroll
            for (int fi = 0; fi < 4; ++fi)
                #pragma unroll
                for (int fj = 0; fj < 4; ++fj)
                    acc[fi][fj] = __builtin_amdgcn_mfma_f32_16x16x32_f16(
                        a_[fi], b_[fj], acc[fi][fj], 0, 0, 0);

            if ((t & 15) == 15) {   // end of a jt: fold into row-min
                const int jt = jt_begin + (t >> 4);
                #pragma unroll
                for (int fj = 0; fj < 4; ++fj) {
                    int j = jt * BN + wc + fj * 16 + tr;
                    float nbv = nb[j];                 // padded with +inf
                    #pragma unroll
                    for (int fi = 0; fi < 4; ++fi)
                        #pragma unroll
                        for (int r = 0; r < 4; ++r) {
                            float s = fmaf(-2.f, acc[fi][fj][r], nbv);
                            localmin[fi * 4 + r] = fminf(localmin[fi * 4 + r], s);
                        }
                }
                #pragma unroll
                for (int fi = 0; fi < 4; ++fi)
                    #pragma unroll
                    for (int fj = 0; fj < 4; ++fj) acc[fi][fj] = (f32x4)0.f;
            }

            __syncthreads();       // drains prefetch vmcnt + lgkm
            cur ^= 1;
        }
    }

    #pragma unroll
    for (int u = 0; u < 16; ++u) {
        float v = localmin[u];
        #pragma unroll
        for (int m = 1; m < 16; m <<= 1) v = fminf(v, __shfl_xor(v, m, 64));
        localmin[u] = v;
    }
    if (tr == 0) {
        #pragma unroll
        for (int fi = 0; fi < 4; ++fi)
            #pragma unroll
            for (int r = 0; r < 4; ++r) {
                int i = tile * BM + wr + fi * 16 + tg * 4 + r;
                if (i < N) {
                    float v = fmaxf(na[i] + localmin[fi * 4 + r], 0.f);
                    atomicMin(&vmin[i], __float_as_uint(v));
                }
            }
    }
}

// ---------------------------------------------------------------------------
// Kernel 2b: fallback (ws too small) — bf16 3-pass, 128x128, in-staging conv.
// ---------------------------------------------------------------------------
__global__ __launch_bounds__(256, 2) void gemm_min_fused(
    const float* __restrict__ A, const float* __restrict__ B,
    const float* __restrict__ na, const float* __restrict__ nb,
    unsigned* __restrict__ vmin, int N, int M, int njt)
{
    __shared__ ushort Ah[4096], Al[4096], Bh[4096], Bl[4096];

    const int tid  = threadIdx.x;
    const int lane = tid & 63;
    const int wave = tid >> 6;
    const int wr = (wave >> 1) * 64;
    const int wc = (wave & 1) * 64;
    const int tr = lane & 15;
    const int tg = lane >> 4;
    const int i0 = blockIdx.y * BM;

    const int sm = tid & 127;
    const int sh = tid >> 7;

    const int per = (njt + JCHUNKS - 1) / JCHUNKS;
    const int jt_begin = min((int)blockIdx.x * per, njt);
    const int jt_end   = min(jt_begin + per, njt);

    float localmin[16];
    #pragma unroll
    for (int u = 0; u < 16; ++u) localmin[u] = __builtin_inff();

    for (int jt = jt_begin; jt < jt_end; ++jt) {
        const int j0 = jt * BN;
        f32x4 acc[4][4];
        #pragma unroll
        for (int fi = 0; fi < 4; ++fi)
            #pragma unroll
            for (int fj = 0; fj < 4; ++fj) acc[fi][fj] = (f32x4)0.f;

        for (int kt = 0; kt < K_DIM / BK; ++kt) {
            const int k0 = kt * BK + sh * 16;
            {
                float f[16];
                int gi = i0 + sm;
                if (gi < N) {
                    const float* p = A + (size_t)gi * K_DIM + k0;
                    #pragma unroll
                    for (int q = 0; q < 4; ++q) {
                        float4 x = *(const float4*)(p + q * 4);
                        f[q*4+0]=x.x; f[q*4+1]=x.y; f[q*4+2]=x.z; f[q*4+3]=x.w;
                    }
                } else {
                    #pragma unroll
                    for (int q = 0; q < 16; ++q) f[q] = 0.f;
                }
                short8 h0, h1, l0, l1;
                #pragma unroll
                for (int q = 0; q < 8; ++q) {
                    uint u = __float_as_uint(f[q]);
                    h0[q] = (short)(u >> 16);
                    float lo = f[q] - __uint_as_float(u & 0xffff0000u);
                    l0[q] = (short)(__float_as_uint(lo) >> 16);
                }
                #pragma unroll
                for (int q = 0; q < 8; ++q) {
                    uint u = __float_as_uint(f[8+q]);
                    h1[q] = (short)(u >> 16);
                    float lo = f[8+q] - __uint_as_float(u & 0xffff0000u);
                    l1[q] = (short)(__float_as_uint(lo) >> 16);
                }
                int g0 = sh * 2;
                *(short8*)(Ah + (g0 * 128 + sm) * 8)       = h0;
                *(short8*)(Ah + ((g0 + 1) * 128 + sm) * 8) = h1;
                *(short8*)(Al + (g0 * 128 + sm) * 8)       = l0;
                *(short8*)(Al + ((g0 + 1) * 128 + sm) * 8) = l1;
            }
            {
                float f[16];
                int gj = j0 + sm;
                if (gj < M) {
                    const float* p = B + (size_t)gj * K_DIM + k0;
                    #pragma unroll
                    for (int q = 0; q < 4; ++q) {
                        float4 x = *(const float4*)(p + q * 4);
                        f[q*4+0]=x.x; f[q*4+1]=x.y; f[q*4+2]=x.z; f[q*4+3]=x.w;
                    }
                } else {
                    #pragma unroll
                    for (int q = 0; q < 16; ++q) f[q] = 0.f;
                }
                short8 h0, h1, l0, l1;
                #pragma unroll
                for (int q = 0; q < 8; ++q) {
                    uint u = __float_as_uint(f[q]);
                    h0[q] = (short)(u >> 16);
                    float lo = f[q] - __uint_as_float(u & 0xffff0000u);
                    l0[q] = (short)(__float_as_uint(lo) >> 16);
                }
                #pragma unroll
                for (int q = 0; q < 8; ++q) {
                    uint u = __float_as_uint(f[8+q]);
                    h1[q] = (short)(u >> 16);
                    float lo = f[8+q] - __uint_as_float(u & 0xffff0000u);
                    l1[q] = (short)(__float_as_uint(lo) >> 16);
                }
                int g0 = sh * 2;
                *(short8*)(Bh + (g0 * 128 + sm) * 8)       = h0;
                *(short8*)(Bh + ((g0 + 1) * 128 + sm) * 8) = h1;
                *(short8*)(Bl + (g0 * 128 + sm) * 8)       = l0;
                *(short8*)(Bl + ((g0 + 1) * 128 + sm) * 8) = l1;
            }
            __syncthreads();

            bf16x8 a_h[4], a_l[4], b_h[4], b_l[4];
            #pragma unroll
            for (int fi = 0; fi < 4; ++fi) {
                int ra = (tg * 128 + wr + fi * 16 + tr) * 8;
                a_h[fi] = *(const bf16x8*)(Ah + ra);
                a_l[fi] = *(const bf16x8*)(Al + ra);
            }
            #pragma unroll
            for (int fj = 0; fj < 4; ++fj) {
                int rb = (tg * 128 + wc + fj * 16 + tr) * 8;
                b_h[fj] = *(const bf16x8*)(Bh + rb);
                b_l[fj] = *(const bf16x8*)(Bl + rb);
            }
            #pragma unroll
            for (int fi = 0; fi < 4; ++fi)
                #pragma unroll
                for (int fj = 0; fj < 4; ++fj) {
                    acc[fi][fj] = __builtin_amdgcn_mfma_f32_16x16x32_bf16(a_h[fi], b_h[fj], acc[fi][fj], 0, 0, 0);
                    acc[fi][fj] = __builtin_amdgcn_mfma_f32_16x16x32_bf16(a_h[fi], b_l[fj], acc[fi][fj], 0, 0, 0);
                    acc[fi][fj] = __builtin_amdgcn_mfma_f32_16x16x32_bf16(a_l[fi], b_h[fj], acc[fi][fj], 0, 0, 0);
                }
            __syncthreads();
        }

        #pragma unroll
        for (int fj = 0; fj < 4; ++fj) {
            int j = j0 + wc + fj * 16 + tr;
            float nbv = nb[j];
            #pragma unroll
            for (int fi = 0; fi < 4; ++fi)
                #pragma unroll
                for (int r = 0; r < 4; ++r) {
                    float s = fmaf(-2.f, acc[fi][fj][r], nbv);
                    localmin[fi * 4 + r] = fminf(localmin[fi * 4 + r], s);
                }
        }
    }

    #pragma unroll
    for (int u = 0; u < 16; ++u) {
        float v = localmin[u];
        #pragma unroll
        for (int m = 1; m < 16; m <<= 1) v = fminf(v, __shfl_xor(v, m, 64));
        localmin[u] = v;
    }
    if (tr == 0) {
        #pragma unroll
        for (int fi = 0; fi < 4; ++fi)
            #pragma unroll
            for (int r = 0; r < 4; ++r) {
                int i = i0 + wr + fi * 16 + tg * 4 + r;
                if (i < N) {
                    float v = fmaxf(na[i] + localmin[fi * 4 + r], 0.f);
                    atomicMin(&vmin[i], __float_as_uint(v));
                }
            }
    }
}

// ---------------------------------------------------------------------------
// Kernel 3: parallel max of vmin (128 blocks, device atomicMax).
// ---------------------------------------------------------------------------
__global__ __launch_bounds__(256) void maxred_kernel(
    const unsigned* __restrict__ vmin, unsigned* __restrict__ maxout, int N)
{
    unsigned best = 0u;
    for (int i = blockIdx.x * 256 + threadIdx.x; i < N; i += gridDim.x * 256) {
        unsigned v = vmin[i];
        if (v > best) best = v;
    }
    #pragma unroll
    for (int m = 1; m < 64; m <<= 1) {
        unsigned o = __shfl_xor(best, m, 64);
        if (o > best) best = o;
    }
    __shared__ unsigned sb[4];
    int lane = threadIdx.x & 63, w = threadIdx.x >> 6;
    if (lane == 0) sb[w] = best;
    __syncthreads();
    if (threadIdx.x == 0) {
        unsigned b = sb[0];
        #pragma unroll
        for (int w2 = 1; w2 < 4; ++w2) if (sb[w2] > b) b = sb[w2];
        atomicMax(maxout, b);
    }
}

// ---------------------------------------------------------------------------
// Kernel 4: collect candidate rows within WINDOW of the approx max.
// ---------------------------------------------------------------------------
__global__ __launch_bounds__(256) void cand_kernel(
    const unsigned* __restrict__ vmin, const unsigned* __restrict__ maxout,
    int* __restrict__ counter, int* __restrict__ list, int N)
{
    int i = blockIdx.x * 256 + threadIdx.x;
    if (i >= N) return;
    float thr = __uint_as_float(*maxout) - WINDOW;
    if (__uint_as_float(vmin[i]) >= thr) {
        int p = atomicAdd(counter, 1);
        if (p < LIST_MAX) list[p] = i;
    }
}

// ---------------------------------------------------------------------------
// Kernel 5: exact fp32 refinement, parallel over (candidate, j-slice).
// ---------------------------------------------------------------------------
__global__ __launch_bounds__(256) void refine_kernel(
    const float* __restrict__ A, const float* __restrict__ B,
    const float* __restrict__ na, const float* __restrict__ nb,
    const int* __restrict__ counter, const int* __restrict__ list,
    unsigned* __restrict__ vminx, int M)
{
    __shared__ float arow[K_DIM];
    __shared__ float sred[4];
    const int tid = threadIdx.x, lane = tid & 63, w = tid >> 6;
    int cnt = *counter;
    if (cnt > LIST_MAX) cnt = LIST_MAX;
    const int slice = (M + NSLICE - 1) / NSLICE;   // ~157

    for (int idx = blockIdx.x; idx < cnt * NSLICE; idx += gridDim.x) {
        const int c = idx / NSLICE;
        const int s = idx % NSLICE;
        const int i = list[c];
        const int j0 = s * slice;
        const int j1 = min(j0 + slice, M);

        __syncthreads();                           // protect arow/sred reuse
        for (int k = tid; k < K_DIM; k += 256)
            arow[k] = A[(size_t)i * K_DIM + k];
        __syncthreads();

        float4 a0 = *(const float4*)&arow[lane * 8];
        float4 a1 = *(const float4*)&arow[lane * 8 + 4];
        float lmin = __builtin_inff();
        for (int j = j0 + w; j < j1; j += 4) {     // wave w takes every 4th j
            const float* br = B + (size_t)j * K_DIM + lane * 8;
            float4 x0 = *(const float4*)br;
            float4 x1 = *(const float4*)(br + 4);
            float d = x0.x*a0.x + x0.y*a0.y + x0.z*a0.z + x0.w*a0.w
                    + x1.x*a1.x + x1.y*a1.y + x1.z*a1.z + x1.w*a1.w;
            #pragma unroll
            for (int m = 1; m < 64; m <<= 1) d += __shfl_xor(d, m, 64);
            float y = fmaf(-2.f, d, nb[j]);
            lmin = fminf(lmin, y);
        }
        if (lane == 0) sred[w] = lmin;
        __syncthreads();
        if (tid == 0) {
            float m2 = fminf(fminf(sred[0], sred[1]), fminf(sred[2], sred[3]));
            float v = fmaxf(na[i] + m2, 0.f);
            atomicMin(&vminx[c], __float_as_uint(v));
        }
    }
}

// ---------------------------------------------------------------------------
// Kernel 6: final — packed max over candidates' exact values, sqrt, write out.
// ---------------------------------------------------------------------------
__global__ __launch_bounds__(1024) void final_kernel(
    const int* __restrict__ counter, const int* __restrict__ list,
    const unsigned* __restrict__ vminx, float* __restrict__ out)
{
    int cnt = *counter;
    if (cnt > LIST_MAX) cnt = LIST_MAX;
    unsigned long long best = 0ull;
    for (int c = threadIdx.x; c < cnt; c += 1024) {
        unsigned long long p =
            ((unsigned long long)vminx[c] << 32) | (unsigned)(~list[c]);
        if (p > best) best = p;
    }
    #pragma unroll
    for (int m = 1; m < 64; m <<= 1) {
        unsigned hi = (unsigned)(best >> 32), lo = (unsigned)best;
        unsigned ohi = __shfl_xor(hi, m, 64);
        unsigned olo = __shfl_xor(lo, m, 64);
        unsigned long long o = ((unsigned long long)ohi << 32) | olo;
        if (o > best) best = o;
    }
    __shared__ unsigned long long sb[16];
    int lane = threadIdx.x & 63, w = threadIdx.x >> 6;
    if (lane == 0) sb[w] = best;
    __syncthreads();
    if (threadIdx.x == 0) {
        unsigned long long b = sb[0];
        #pragma unroll
        for (int w2 = 1; w2 < 16; ++w2) if (sb[w2] > b) b = sb[w2];
        out[0] = (float)(~(unsigned)(b & 0xFFFFFFFFull));
        out[1] = sqrtf(__uint_as_float((unsigned)(b >> 32)));
    }
}

// ---------------------------------------------------------------------------
extern "C" void kernel_launch(void* const* d_in, const int* in_sizes, int n_in,
                              void* d_out, int out_size, void* d_ws, size_t ws_size,
                              hipStream_t stream)
{
    const float* A = (const float*)d_in[0];
    const float* B = (const float*)d_in[1];
    const int N = in_sizes[0] / K_DIM;           // 50000
    const int M = in_sizes[1] / K_DIM;           // 5000
    const int ntile = (N + BM - 1) / BM;         // 391
    const int njt   = (M + BN - 1) / BN;         // 40
    const int Npad = ntile * BM, Mpad = njt * BN;

    char* ws = (char*)d_ws;
    float*    na   = (float*)ws;                     // Npad
    float*    nb   = na + Npad;                      // Mpad
    unsigned* vmin = (unsigned*)(nb + Mpad);         // Npad
    size_t off0 = ((size_t)(Npad + Mpad + Npad) * 4 + 255) & ~(size_t)255;
    ushort* AhW = (ushort*)(ws + off0);              // Npad*512 f16
    ushort* BhW = AhW + (size_t)Npad * K_DIM;        // Mpad*512 f16
    size_t off1 = (off0 + ((size_t)Npad + Mpad) * K_DIM * 2 + 255) & ~(size_t)255;
    unsigned* maxout = (unsigned*)(ws + off1);
    int* counter = (int*)(maxout + 1);
    int* list    = counter + 1;                      // LIST_MAX ints
    unsigned* vminx = (unsigned*)(list + LIST_MAX);  // LIST_MAX uints
    size_t need = off1 + 16 + (size_t)LIST_MAX * 8;

    float* out = (float*)d_out;

    int waves = Npad + Mpad;
    hipLaunchKernelGGL(norms_init_kernel, dim3((waves + 3) / 4), dim3(256), 0, stream,
                       A, B, na, nb, vmin, vminx, counter, maxout, N, M, Npad, Mpad);

    if (ws_size >= need) {
        hipLaunchKernelGGL(preconvert_f16_kernel, dim3((Npad * 64 + 255) / 256), dim3(256), 0, stream,
                           A, AhW, N, Npad);
        hipLaunchKernelGGL(preconvert_f16_kernel, dim3((Mpad * 64 + 255) / 256), dim3(256), 0, stream,
                           B, BhW, M, Mpad);
        hipLaunchKernelGGL(gemm_min_f16, dim3(JCHUNKS, ntile), dim3(256), 0, stream,
                           AhW, BhW, na, nb, vmin, N, njt);
    } else {
        hipLaunchKernelGGL(gemm_min_fused, dim3(JCHUNKS, ntile), dim3(256), 0, stream,
                           A, B, na, nb, vmin, N, M, njt);
    }

    hipLaunchKernelGGL(maxred_kernel, dim3(128), dim3(256), 0, stream,
                       vmin, maxout, N);
    hipLaunchKernelGGL(cand_kernel, dim3((N + 255) / 256), dim3(256), 0, stream,
                       vmin, maxout, counter, list, N);
    hipLaunchKernelGGL(refine_kernel, dim3(REF_GRID), dim3(256), 0, stream,
                       A, B, na, nb, counter, list, vminx, M);
    hipLaunchKernelGGL(final_kernel, dim3(1), dim3(1024), 0, stream,
                       counter, list, vminx, out);
}